// Round 1
// baseline (269.861 us; speedup 1.0000x reference)
//
#include <hip/hip_runtime.h>
#include <hip/hip_bf16.h>

// Talking-heads attention + GFSA reaction, MI355X (gfx950).
// Decomposition: attn_final = (1-2λ)A + 3λ A², applied to v:
//   out_ctx = (1-2λ)(A@v) + 3λ A@(A@v)   -- avoids N×N A@A entirely.
// Head mixes (pre/post softmax) fused into one per-row kernel (in-place S->A).

typedef __bf16 bf16x8 __attribute__((ext_vector_type(8)));
typedef float f32x4 __attribute__((ext_vector_type(4)));

#define DI __device__ __forceinline__

DI unsigned short f2bf(float f) {
  union { float f; unsigned u; } x; x.f = f;
  unsigned r = x.u + 0x7FFF + ((x.u >> 16) & 1);   // RNE
  return (unsigned short)(r >> 16);
}
DI float bf2f(unsigned short u) {
  union { unsigned u; float f; } x; x.u = ((unsigned)u) << 16; return x.f;
}

struct GP {
  const unsigned short* A;
  const unsigned short* B;
  int M, N, K, lda, ldb, ldc;
  long sA, sB, sC;
  unsigned short* C;
  const unsigned short* C2;
  float* outF;
  const float* bias;
  const float* lamb;
  unsigned short* q_out;
  unsigned short* k_out;
  unsigned short* vT_out;
};

// C = A @ B^T, A:[M,K] bf16 row-major(lda), B:[N,K] bf16 row-major(ldb).
// 4 waves (256 thr), per-wave 64x64 via 4x4 frags of mfma_f32_16x16x32_bf16.
// BK=64, LDS XOR-swizzle (chunk ^ (row&7)) -> conflict-free-ish ds_read_b128.
template<int WM, int WN, int EPI>
__global__ __launch_bounds__(256) void gemm_bt(GP p) {
  constexpr int BM = WM * 64, BN = WN * 64;
  __shared__ __align__(16) unsigned short lA[BM * 64];
  __shared__ __align__(16) unsigned short lB[BN * 64];
  const int tid = threadIdx.x, lane = tid & 63, wid = tid >> 6;
  const int wr = wid / WN, wc = wid % WN;
  const int m0 = blockIdx.y * BM, n0 = blockIdx.x * BN;
  const int bz = blockIdx.z;
  const unsigned short* Ab = p.A + (long)bz * p.sA;
  const unsigned short* Bb = p.B + (long)bz * p.sB;

  f32x4 acc[4][4];
#pragma unroll
  for (int i = 0; i < 4; ++i)
#pragma unroll
    for (int j = 0; j < 4; ++j) acc[i][j] = (f32x4)0.f;

  for (int k0 = 0; k0 < p.K; k0 += 64) {
    __syncthreads();
#pragma unroll
    for (int i = 0; i < BM / 32; ++i) {
      int c = tid + i * 256, r = c >> 3, kc = c & 7;
      uint4 d = *(const uint4*)(Ab + (long)(m0 + r) * p.lda + k0 + kc * 8);
      *(uint4*)&lA[r * 64 + ((kc ^ (r & 7)) << 3)] = d;
    }
#pragma unroll
    for (int i = 0; i < BN / 32; ++i) {
      int c = tid + i * 256, r = c >> 3, kc = c & 7;
      uint4 d = *(const uint4*)(Bb + (long)(n0 + r) * p.ldb + k0 + kc * 8);
      *(uint4*)&lB[r * 64 + ((kc ^ (r & 7)) << 3)] = d;
    }
    __syncthreads();
#pragma unroll
    for (int half = 0; half < 2; ++half) {
      bf16x8 af[4], bfr[4];
#pragma unroll
      for (int mi = 0; mi < 4; ++mi) {
        int r = wr * 64 + mi * 16 + (lane & 15);
        int kc = half * 4 + (lane >> 4);
        af[mi] = *(const bf16x8*)&lA[r * 64 + ((kc ^ (r & 7)) << 3)];
      }
#pragma unroll
      for (int ni = 0; ni < 4; ++ni) {
        int r = wc * 64 + ni * 16 + (lane & 15);
        int kc = half * 4 + (lane >> 4);
        bfr[ni] = *(const bf16x8*)&lB[r * 64 + ((kc ^ (r & 7)) << 3)];
      }
#pragma unroll
      for (int mi = 0; mi < 4; ++mi)
#pragma unroll
        for (int ni = 0; ni < 4; ++ni)
          acc[mi][ni] = __builtin_amdgcn_mfma_f32_16x16x32_bf16(
              af[mi], bfr[ni], acc[mi][ni], 0, 0, 0);
    }
  }

#pragma unroll
  for (int mi = 0; mi < 4; ++mi)
#pragma unroll
    for (int ni = 0; ni < 4; ++ni)
#pragma unroll
      for (int r2 = 0; r2 < 4; ++r2) {
        int row = m0 + wr * 64 + mi * 16 + (lane >> 4) * 4 + r2;
        int col = n0 + wc * 64 + ni * 16 + (lane & 15);
        float v = acc[mi][ni][r2];
        if constexpr (EPI == 0) {          // plain bf16 store
          p.C[(long)bz * p.sC + (long)row * p.ldc + col] = f2bf(v);
        } else if constexpr (EPI == 1) {   // qkv scatter: q*SCALE, k, v^T
          int b = row >> 10, n = row & 1023;
          int s = col / 768, rem = col - s * 768;
          int h = rem >> 6, d = rem & 63;
          long ho = (long)(b * 12 + h);
          if (s == 0)      p.q_out[(ho * 1024 + n) * 64 + d] = f2bf(v * 0.125f);
          else if (s == 1) p.k_out[(ho * 1024 + n) * 64 + d] = f2bf(v);
          else             p.vT_out[(ho * 64 + d) * 1024 + n] = f2bf(v);
        } else if constexpr (EPI == 2) {   // fp32 out + bias
          p.outF[(long)row * p.ldc + col] = v + p.bias[col];
        } else if constexpr (EPI == 4) {   // ctx = (1-2λ)U + 3λ·Y
          int b = bz / 12, h = bz - b * 12;
          float lam = p.lamb[h];
          float Uv = bf2f(p.C2[(long)bz * 65536 + col * 1024 + row]);
          float val = (1.f - 2.f * lam) * Uv + 3.f * lam * v;
          p.C[((long)(b * 1024 + row)) * 768 + h * 64 + col] = f2bf(val);
        }
      }
}

// One block per (b,n) row: pre-mix over heads -> softmax -> post-mix,
// reading S[b,h,n,:] for all h and writing A[b,g,n,:] in place.
__global__ __launch_bounds__(256) void mix_softmax(
    unsigned short* S, const float* W1, const float* b1,
    const float* W2, const float* b2) {
  __shared__ float rowbuf[12][1024];
  __shared__ float w1s[144], w2s[144], b1s[12], b2s[12], rsum[12];
  const int tid = threadIdx.x;
  const int bn = blockIdx.x;
  const int b = bn >> 10, n = bn & 1023;
  if (tid < 144) { w1s[tid] = W1[tid]; w2s[tid] = W2[tid]; }
  if (tid < 12) { b1s[tid] = b1[tid]; b2s[tid] = b2[tid]; }
  unsigned short* Sb = S + ((long)(b * 12) * 1024 + n) * 1024;
#pragma unroll
  for (int h = 0; h < 12; ++h) {
    const unsigned short* src = Sb + (long)h * 1024 * 1024;
    ushort4 vv = *(const ushort4*)(src + tid * 4);
    rowbuf[h][tid * 4 + 0] = bf2f(vv.x);
    rowbuf[h][tid * 4 + 1] = bf2f(vv.y);
    rowbuf[h][tid * 4 + 2] = bf2f(vv.z);
    rowbuf[h][tid * 4 + 3] = bf2f(vv.w);
  }
  __syncthreads();
  float L[12][4];
#pragma unroll
  for (int j = 0; j < 4; ++j) {
    int m = tid + j * 256;
    float sv[12];
#pragma unroll
    for (int h = 0; h < 12; ++h) sv[h] = rowbuf[h][m];
#pragma unroll
    for (int g = 0; g < 12; ++g) {
      float a = b1s[g];
#pragma unroll
      for (int h = 0; h < 12; ++h) a += w1s[g * 12 + h] * sv[h];
      L[g][j] = a;
    }
  }
  __syncthreads();
#pragma unroll
  for (int g = 0; g < 12; ++g)
#pragma unroll
    for (int j = 0; j < 4; ++j) rowbuf[g][tid + j * 256] = L[g][j];
  __syncthreads();
  const int wid2 = tid >> 6, lane = tid & 63;
  for (int gi = 0; gi < 3; ++gi) {
    int g = wid2 * 3 + gi;
    float mx = -1e30f;
#pragma unroll
    for (int i = 0; i < 16; ++i) mx = fmaxf(mx, rowbuf[g][lane + i * 64]);
#pragma unroll
    for (int o = 32; o > 0; o >>= 1) mx = fmaxf(mx, __shfl_xor(mx, o));
    float sm = 0.f;
#pragma unroll
    for (int i = 0; i < 16; ++i) {
      float e = __expf(rowbuf[g][lane + i * 64] - mx);
      rowbuf[g][lane + i * 64] = e;
      sm += e;
    }
#pragma unroll
    for (int o = 32; o > 0; o >>= 1) sm += __shfl_xor(sm, o);
    if (lane == 0) rsum[g] = 1.f / sm;
  }
  __syncthreads();
#pragma unroll
  for (int j = 0; j < 4; ++j) {
    int m = tid + j * 256;
    float pp[12];
#pragma unroll
    for (int h = 0; h < 12; ++h) pp[h] = rowbuf[h][m] * rsum[h];
#pragma unroll
    for (int g = 0; g < 12; ++g) {
      float a = b2s[g];
#pragma unroll
      for (int h = 0; h < 12; ++h) a += w2s[g * 12 + h] * pp[h];
      Sb[(long)g * 1024 * 1024 + m] = f2bf(a);
    }
  }
}

__global__ __launch_bounds__(256) void f2bf_vec(const float* in,
                                                unsigned short* out, int n4) {
  int i = blockIdx.x * blockDim.x + threadIdx.x;
  if (i < n4) {
    float4 v = *(const float4*)(in + (long)i * 4);
    ushort4 o;
    o.x = f2bf(v.x); o.y = f2bf(v.y); o.z = f2bf(v.z); o.w = f2bf(v.w);
    *(ushort4*)(out + (long)i * 4) = o;
  }
}

extern "C" void kernel_launch(void* const* d_in, const int* in_sizes, int n_in,
                              void* d_out, int out_size, void* d_ws,
                              size_t ws_size, hipStream_t stream) {
  const float* x     = (const float*)d_in[0];
  const float* qkv_w = (const float*)d_in[1];
  const float* W1    = (const float*)d_in[2];
  const float* b1    = (const float*)d_in[3];
  const float* W2    = (const float*)d_in[4];
  const float* b2    = (const float*)d_in[5];
  const float* lamb  = (const float*)d_in[6];
  const float* Wout  = (const float*)d_in[7];
  const float* bout  = (const float*)d_in[8];
  float* out = (float*)d_out;

  char* ws = (char*)d_ws;
  size_t off = 0;
  auto alloc = [&](size_t bytes) {
    char* p = ws + off;
    off = (off + bytes + 255) & ~(size_t)255;
    return p;
  };
  unsigned short* Sbuf    = (unsigned short*)alloc(48ull * 1024 * 1024 * 2);
  unsigned short* x_bf    = (unsigned short*)alloc(4096ull * 768 * 2);
  unsigned short* wqkv_bf = (unsigned short*)alloc(2304ull * 768 * 2);
  unsigned short* wout_bf = (unsigned short*)alloc(768ull * 768 * 2);
  unsigned short* q_bf    = (unsigned short*)alloc(48ull * 1024 * 64 * 2);
  unsigned short* k_bf    = (unsigned short*)alloc(48ull * 1024 * 64 * 2);
  unsigned short* vT_bf   = (unsigned short*)alloc(48ull * 64 * 1024 * 2);
  unsigned short* UT      = (unsigned short*)alloc(48ull * 64 * 1024 * 2);
  unsigned short* ctx     = (unsigned short*)alloc(4096ull * 768 * 2);
  if (off > ws_size) return;  // ws insufficient -> leaves output zero (signal)

  f2bf_vec<<<dim3(4096 * 768 / 4 / 256), 256, 0, stream>>>(x, x_bf, 4096 * 768 / 4);
  f2bf_vec<<<dim3(2304 * 768 / 4 / 256), 256, 0, stream>>>(qkv_w, wqkv_bf, 2304 * 768 / 4);
  f2bf_vec<<<dim3(768 * 768 / 4 / 256), 256, 0, stream>>>(Wout, wout_bf, 768 * 768 / 4);

  {  // GEMM1: qkv = x @ qkv_w^T, scatter q/k/vT
    GP p{};
    p.A = x_bf; p.B = wqkv_bf;
    p.M = 4096; p.N = 2304; p.K = 768; p.lda = 768; p.ldb = 768;
    p.q_out = q_bf; p.k_out = k_bf; p.vT_out = vT_bf;
    gemm_bt<2, 2, 1><<<dim3(18, 32, 1), 256, 0, stream>>>(p);
  }
  {  // GEMM2: S[b,h] = q @ k^T   (48 batches)
    GP p{};
    p.A = q_bf; p.B = k_bf;
    p.M = 1024; p.N = 1024; p.K = 64; p.lda = 64; p.ldb = 64;
    p.sA = 65536; p.sB = 65536;
    p.C = Sbuf; p.sC = 1048576; p.ldc = 1024;
    gemm_bt<2, 2, 0><<<dim3(8, 8, 48), 256, 0, stream>>>(p);
  }
  mix_softmax<<<dim3(4096), 256, 0, stream>>>(Sbuf, W1, b1, W2, b2);
  {  // GEMM3: UT[b,h] = vT @ A^T  (U = A@v, stored transposed [64][1024])
    GP p{};
    p.A = vT_bf; p.B = Sbuf;
    p.M = 64; p.N = 1024; p.K = 1024; p.lda = 1024; p.ldb = 1024;
    p.sA = 65536; p.sB = 1048576;
    p.C = UT; p.sC = 65536; p.ldc = 1024;
    gemm_bt<1, 4, 0><<<dim3(4, 1, 48), 256, 0, stream>>>(p);
  }
  {  // GEMM4: Y = A @ U; ctx = (1-2λ)U + 3λY  (per-head scatter into [B,N,C])
    GP p{};
    p.A = Sbuf; p.B = UT;
    p.M = 1024; p.N = 64; p.K = 1024; p.lda = 1024; p.ldb = 1024;
    p.sA = 1048576; p.sB = 65536;
    p.C = ctx; p.C2 = UT; p.lamb = lamb;
    gemm_bt<4, 1, 4><<<dim3(1, 4, 48), 256, 0, stream>>>(p);
  }
  {  // GEMM5: out = ctx @ Wout^T + bout  (fp32 out)
    GP p{};
    p.A = ctx; p.B = wout_bf;
    p.M = 4096; p.N = 768; p.K = 768; p.lda = 768; p.ldb = 768;
    p.outF = out; p.bias = bout; p.ldc = 768;
    gemm_bt<2, 2, 2><<<dim3(6, 32, 1), 256, 0, stream>>>(p);
  }
}

// Round 2
// 232.919 us; speedup vs baseline: 1.1586x; 1.1586x over previous
//
#include <hip/hip_runtime.h>
#include <hip/hip_bf16.h>

// Talking-heads attention + GFSA reaction, MI355X (gfx950).
// Decomposition: attn_final = (1-2λ)A + 3λ A², applied to v:
//   out_ctx = (1-2λ)(A@v) + 3λ A@(A@v)   -- avoids N×N A@A entirely.
// Head mixes (pre/post softmax) fused into one per-row kernel (in-place S->A),
// fully register-resident (R1: was LDS-resident, 3 round-trips, 20% occupancy).

typedef __bf16 bf16x8 __attribute__((ext_vector_type(8)));
typedef float f32x4 __attribute__((ext_vector_type(4)));

#define DI __device__ __forceinline__

DI unsigned short f2bf(float f) {
  union { float f; unsigned u; } x; x.f = f;
  unsigned r = x.u + 0x7FFF + ((x.u >> 16) & 1);   // RNE
  return (unsigned short)(r >> 16);
}
DI float bf2f(unsigned short u) {
  union { unsigned u; float f; } x; x.u = ((unsigned)u) << 16; return x.f;
}

struct GP {
  const unsigned short* A;
  const unsigned short* B;
  int M, N, K, lda, ldb, ldc;
  long sA, sB, sC;
  unsigned short* C;
  const unsigned short* C2;
  float* outF;
  const float* bias;
  const float* lamb;
  unsigned short* q_out;
  unsigned short* k_out;
  unsigned short* vT_out;
};

// C = A @ B^T, A:[M,K] bf16 row-major(lda), B:[N,K] bf16 row-major(ldb).
// 4 waves (256 thr), per-wave 64x64 via 4x4 frags of mfma_f32_16x16x32_bf16.
// BK=64, LDS XOR-swizzle (chunk ^ (row&7)) -> conflict-free-ish ds_read_b128.
template<int WM, int WN, int EPI>
__global__ __launch_bounds__(256) void gemm_bt(GP p) {
  constexpr int BM = WM * 64, BN = WN * 64;
  __shared__ __align__(16) unsigned short lA[BM * 64];
  __shared__ __align__(16) unsigned short lB[BN * 64];
  const int tid = threadIdx.x, lane = tid & 63, wid = tid >> 6;
  const int wr = wid / WN, wc = wid % WN;
  const int m0 = blockIdx.y * BM, n0 = blockIdx.x * BN;
  const int bz = blockIdx.z;
  const unsigned short* Ab = p.A + (long)bz * p.sA;
  const unsigned short* Bb = p.B + (long)bz * p.sB;

  f32x4 acc[4][4];
#pragma unroll
  for (int i = 0; i < 4; ++i)
#pragma unroll
    for (int j = 0; j < 4; ++j) acc[i][j] = (f32x4)0.f;

  for (int k0 = 0; k0 < p.K; k0 += 64) {
    __syncthreads();
#pragma unroll
    for (int i = 0; i < BM / 32; ++i) {
      int c = tid + i * 256, r = c >> 3, kc = c & 7;
      uint4 d = *(const uint4*)(Ab + (long)(m0 + r) * p.lda + k0 + kc * 8);
      *(uint4*)&lA[r * 64 + ((kc ^ (r & 7)) << 3)] = d;
    }
#pragma unroll
    for (int i = 0; i < BN / 32; ++i) {
      int c = tid + i * 256, r = c >> 3, kc = c & 7;
      uint4 d = *(const uint4*)(Bb + (long)(n0 + r) * p.ldb + k0 + kc * 8);
      *(uint4*)&lB[r * 64 + ((kc ^ (r & 7)) << 3)] = d;
    }
    __syncthreads();
#pragma unroll
    for (int half = 0; half < 2; ++half) {
      bf16x8 af[4], bfr[4];
#pragma unroll
      for (int mi = 0; mi < 4; ++mi) {
        int r = wr * 64 + mi * 16 + (lane & 15);
        int kc = half * 4 + (lane >> 4);
        af[mi] = *(const bf16x8*)&lA[r * 64 + ((kc ^ (r & 7)) << 3)];
      }
#pragma unroll
      for (int ni = 0; ni < 4; ++ni) {
        int r = wc * 64 + ni * 16 + (lane & 15);
        int kc = half * 4 + (lane >> 4);
        bfr[ni] = *(const bf16x8*)&lB[r * 64 + ((kc ^ (r & 7)) << 3)];
      }
#pragma unroll
      for (int mi = 0; mi < 4; ++mi)
#pragma unroll
        for (int ni = 0; ni < 4; ++ni)
          acc[mi][ni] = __builtin_amdgcn_mfma_f32_16x16x32_bf16(
              af[mi], bfr[ni], acc[mi][ni], 0, 0, 0);
    }
  }

#pragma unroll
  for (int mi = 0; mi < 4; ++mi)
#pragma unroll
    for (int ni = 0; ni < 4; ++ni)
#pragma unroll
      for (int r2 = 0; r2 < 4; ++r2) {
        int row = m0 + wr * 64 + mi * 16 + (lane >> 4) * 4 + r2;
        int col = n0 + wc * 64 + ni * 16 + (lane & 15);
        float v = acc[mi][ni][r2];
        if constexpr (EPI == 0) {          // plain bf16 store
          p.C[(long)bz * p.sC + (long)row * p.ldc + col] = f2bf(v);
        } else if constexpr (EPI == 1) {   // qkv scatter: q*SCALE, k, v^T
          int b = row >> 10, n = row & 1023;
          int s = col / 768, rem = col - s * 768;
          int h = rem >> 6, d = rem & 63;
          long ho = (long)(b * 12 + h);
          if (s == 0)      p.q_out[(ho * 1024 + n) * 64 + d] = f2bf(v * 0.125f);
          else if (s == 1) p.k_out[(ho * 1024 + n) * 64 + d] = f2bf(v);
          else             p.vT_out[(ho * 64 + d) * 1024 + n] = f2bf(v);
        } else if constexpr (EPI == 2) {   // fp32 out + bias
          p.outF[(long)row * p.ldc + col] = v + p.bias[col];
        } else if constexpr (EPI == 4) {   // ctx = (1-2λ)U + 3λ·Y
          int b = bz / 12, h = bz - b * 12;
          float lam = p.lamb[h];
          float Uv = bf2f(p.C2[(long)bz * 65536 + col * 1024 + row]);
          float val = (1.f - 2.f * lam) * Uv + 3.f * lam * v;
          p.C[((long)(b * 1024 + row)) * 768 + h * 64 + col] = f2bf(val);
        }
      }
}

// One block per (b,n) row: pre-mix over heads -> softmax -> post-mix,
// reading S[b,h,n,:] for all h and writing A[b,g,n,:] in place.
// Fully register-resident: each thread owns 4 columns x 12 heads (L[12][4]).
// Softmax reductions: 6-step shuffle across 64 lanes + 4x12 LDS cross-wave.
__global__ __launch_bounds__(256) void mix_softmax(
    unsigned short* S, const float* W1, const float* b1,
    const float* W2, const float* b2) {
  __shared__ float w1s[144], w2s[144], b1s[12], b2s[12];
  __shared__ float red[4][12];
  const int tid = threadIdx.x, lane = tid & 63, wid = tid >> 6;
  if (tid < 144) { w1s[tid] = W1[tid]; w2s[tid] = W2[tid]; }
  if (tid < 12) { b1s[tid] = b1[tid]; b2s[tid] = b2[tid]; }
  const int bn = blockIdx.x;
  const int b = bn >> 10, n = bn & 1023;
  unsigned short* Sb = S + ((long)(b * 12) * 1024 + n) * 1024 + tid * 4;
  __syncthreads();

  float L[12][4];
#pragma unroll
  for (int g = 0; g < 12; ++g)
#pragma unroll
    for (int j = 0; j < 4; ++j) L[g][j] = b1s[g];
#pragma unroll
  for (int h = 0; h < 12; ++h) {
    ushort4 vv = *(const ushort4*)(Sb + (long)h * 1048576);
    float f0 = bf2f(vv.x), f1 = bf2f(vv.y), f2 = bf2f(vv.z), f3 = bf2f(vv.w);
#pragma unroll
    for (int g = 0; g < 12; ++g) {
      float w = w1s[g * 12 + h];
      L[g][0] += w * f0; L[g][1] += w * f1;
      L[g][2] += w * f2; L[g][3] += w * f3;
    }
  }
  // per-head max over 1024 cols: 4 in-reg + 64-lane shuffle + cross-wave LDS
  float rv[12];
#pragma unroll
  for (int g = 0; g < 12; ++g) {
    float m = fmaxf(fmaxf(L[g][0], L[g][1]), fmaxf(L[g][2], L[g][3]));
#pragma unroll
    for (int o = 32; o > 0; o >>= 1) m = fmaxf(m, __shfl_xor(m, o));
    rv[g] = m;
  }
  if (lane == 0) {
#pragma unroll
    for (int g = 0; g < 12; ++g) red[wid][g] = rv[g];
  }
  __syncthreads();
  float mxf[12];
#pragma unroll
  for (int g = 0; g < 12; ++g)
    mxf[g] = fmaxf(fmaxf(red[0][g], red[1][g]), fmaxf(red[2][g], red[3][g]));
  __syncthreads();
  // exp + per-head sum
#pragma unroll
  for (int g = 0; g < 12; ++g) {
    float s = 0.f;
#pragma unroll
    for (int j = 0; j < 4; ++j) {
      L[g][j] = __expf(L[g][j] - mxf[g]);
      s += L[g][j];
    }
#pragma unroll
    for (int o = 32; o > 0; o >>= 1) s += __shfl_xor(s, o);
    rv[g] = s;
  }
  if (lane == 0) {
#pragma unroll
    for (int g = 0; g < 12; ++g) red[wid][g] = rv[g];
  }
  __syncthreads();
#pragma unroll
  for (int g = 0; g < 12; ++g) {
    float rinv = 1.f / (red[0][g] + red[1][g] + red[2][g] + red[3][g]);
#pragma unroll
    for (int j = 0; j < 4; ++j) L[g][j] *= rinv;
  }
  // post-mix + store
#pragma unroll
  for (int g = 0; g < 12; ++g) {
    float o0 = b2s[g], o1 = o0, o2 = o0, o3 = o0;
#pragma unroll
    for (int h = 0; h < 12; ++h) {
      float w = w2s[g * 12 + h];
      o0 += w * L[h][0]; o1 += w * L[h][1];
      o2 += w * L[h][2]; o3 += w * L[h][3];
    }
    ushort4 ov;
    ov.x = f2bf(o0); ov.y = f2bf(o1); ov.z = f2bf(o2); ov.w = f2bf(o3);
    *(ushort4*)(Sb + (long)g * 1048576) = ov;
  }
}

__global__ __launch_bounds__(256) void f2bf_vec(const float* in,
                                                unsigned short* out, int n4) {
  int i = blockIdx.x * blockDim.x + threadIdx.x;
  if (i < n4) {
    float4 v = *(const float4*)(in + (long)i * 4);
    ushort4 o;
    o.x = f2bf(v.x); o.y = f2bf(v.y); o.z = f2bf(v.z); o.w = f2bf(v.w);
    *(ushort4*)(out + (long)i * 4) = o;
  }
}

extern "C" void kernel_launch(void* const* d_in, const int* in_sizes, int n_in,
                              void* d_out, int out_size, void* d_ws,
                              size_t ws_size, hipStream_t stream) {
  const float* x     = (const float*)d_in[0];
  const float* qkv_w = (const float*)d_in[1];
  const float* W1    = (const float*)d_in[2];
  const float* b1    = (const float*)d_in[3];
  const float* W2    = (const float*)d_in[4];
  const float* b2    = (const float*)d_in[5];
  const float* lamb  = (const float*)d_in[6];
  const float* Wout  = (const float*)d_in[7];
  const float* bout  = (const float*)d_in[8];
  float* out = (float*)d_out;

  char* ws = (char*)d_ws;
  size_t off = 0;
  auto alloc = [&](size_t bytes) {
    char* p = ws + off;
    off = (off + bytes + 255) & ~(size_t)255;
    return p;
  };
  unsigned short* Sbuf    = (unsigned short*)alloc(48ull * 1024 * 1024 * 2);
  unsigned short* x_bf    = (unsigned short*)alloc(4096ull * 768 * 2);
  unsigned short* wqkv_bf = (unsigned short*)alloc(2304ull * 768 * 2);
  unsigned short* wout_bf = (unsigned short*)alloc(768ull * 768 * 2);
  unsigned short* q_bf    = (unsigned short*)alloc(48ull * 1024 * 64 * 2);
  unsigned short* k_bf    = (unsigned short*)alloc(48ull * 1024 * 64 * 2);
  unsigned short* vT_bf   = (unsigned short*)alloc(48ull * 64 * 1024 * 2);
  unsigned short* UT      = (unsigned short*)alloc(48ull * 64 * 1024 * 2);
  unsigned short* ctx     = (unsigned short*)alloc(4096ull * 768 * 2);
  if (off > ws_size) return;  // ws insufficient -> leaves output zero (signal)

  f2bf_vec<<<dim3(4096 * 768 / 4 / 256), 256, 0, stream>>>(x, x_bf, 4096 * 768 / 4);
  f2bf_vec<<<dim3(2304 * 768 / 4 / 256), 256, 0, stream>>>(qkv_w, wqkv_bf, 2304 * 768 / 4);
  f2bf_vec<<<dim3(768 * 768 / 4 / 256), 256, 0, stream>>>(Wout, wout_bf, 768 * 768 / 4);

  {  // GEMM1: qkv = x @ qkv_w^T, scatter q/k/vT
    GP p{};
    p.A = x_bf; p.B = wqkv_bf;
    p.M = 4096; p.N = 2304; p.K = 768; p.lda = 768; p.ldb = 768;
    p.q_out = q_bf; p.k_out = k_bf; p.vT_out = vT_bf;
    gemm_bt<2, 2, 1><<<dim3(18, 32, 1), 256, 0, stream>>>(p);
  }
  {  // GEMM2: S[b,h] = q @ k^T   (48 batches)
    GP p{};
    p.A = q_bf; p.B = k_bf;
    p.M = 1024; p.N = 1024; p.K = 64; p.lda = 64; p.ldb = 64;
    p.sA = 65536; p.sB = 65536;
    p.C = Sbuf; p.sC = 1048576; p.ldc = 1024;
    gemm_bt<2, 2, 0><<<dim3(8, 8, 48), 256, 0, stream>>>(p);
  }
  mix_softmax<<<dim3(4096), 256, 0, stream>>>(Sbuf, W1, b1, W2, b2);
  {  // GEMM3: UT[b,h] = vT @ A^T  (U = A@v, stored transposed [64][1024])
    GP p{};
    p.A = vT_bf; p.B = Sbuf;
    p.M = 64; p.N = 1024; p.K = 1024; p.lda = 1024; p.ldb = 1024;
    p.sA = 65536; p.sB = 1048576;
    p.C = UT; p.sC = 65536; p.ldc = 1024;
    gemm_bt<1, 4, 0><<<dim3(4, 1, 48), 256, 0, stream>>>(p);
  }
  {  // GEMM4: Y = A @ U; ctx = (1-2λ)U + 3λY  (per-head scatter into [B,N,C])
    GP p{};
    p.A = Sbuf; p.B = UT;
    p.M = 1024; p.N = 64; p.K = 1024; p.lda = 1024; p.ldb = 1024;
    p.sA = 1048576; p.sB = 65536;
    p.C = ctx; p.C2 = UT; p.lamb = lamb;
    gemm_bt<4, 1, 4><<<dim3(1, 4, 48), 256, 0, stream>>>(p);
  }
  {  // GEMM5: out = ctx @ Wout^T + bout  (fp32 out)
    GP p{};
    p.A = ctx; p.B = wout_bf;
    p.M = 4096; p.N = 768; p.K = 768; p.lda = 768; p.ldb = 768;
    p.outF = out; p.bias = bout; p.ldc = 768;
    gemm_bt<2, 2, 2><<<dim3(6, 32, 1), 256, 0, stream>>>(p);
  }
}